// Round 4
// baseline (472.106 us; speedup 1.0000x reference)
//
#include <hip/hip_runtime.h>
#include <hip/hip_bf16.h>
#include <math.h>

#define B_  4
#define N_  1024
#define D_  512
#define H_  8
#define DH_ 64
#define TC_ 512
#define AB_ 16
#define EPS_ 1e-5f
#define NEG_ 1e6f

typedef _Float16 half8v __attribute__((ext_vector_type(8)));
typedef _Float16 half4v __attribute__((ext_vector_type(4)));
typedef float floatx4 __attribute__((ext_vector_type(4)));

// ---------------------------------------------------------------------------
// Fused launch 1: blocks 0..1023  -> FiLM precompute
//                 blocks 1024..2047 -> weight f16 conversion (Wq*0.125, Wkv, Wo)
// ---------------------------------------------------------------------------
__global__ __launch_bounds__(256)
void film_cvtw_kernel(const float* __restrict__ time_in,
                      const float* __restrict__ Wt,
                      const float* __restrict__ bt,
                      float* __restrict__ film,
                      const float* __restrict__ Wq, const float* __restrict__ Wkv,
                      const float* __restrict__ Wo,
                      _Float16* __restrict__ Wqh, _Float16* __restrict__ Wkvh,
                      _Float16* __restrict__ Woh) {
    __shared__ float st[TC_];
    if (blockIdx.x < 1024) {
        // ---- FiLM: film[b,c] = sum_j silu(time[b,j])*Wt[c,j] + bt[c] ----
        int b = blockIdx.x >> 8;
        int cblk = blockIdx.x & 255;
        const float* trow = time_in + b * TC_;
        for (int j = threadIdx.x; j < TC_; j += 256) {
            float tv = trow[j];
            st[j] = tv / (1.f + __expf(-tv));
        }
        __syncthreads();
        int wave = threadIdx.x >> 6, lane = threadIdx.x & 63;
        int c = cblk * 4 + wave;
        const float* wrow = Wt + (size_t)c * TC_;
        float acc = 0.f;
        #pragma unroll
        for (int j0 = 0; j0 < TC_; j0 += 64)
            acc += st[j0 + lane] * wrow[j0 + lane];
        #pragma unroll
        for (int off = 32; off; off >>= 1)
            acc += __shfl_down(acc, off);
        if (lane == 0) film[b * 2 * D_ + c] = acc + bt[c];
    } else {
        // ---- weight cvt: 262144 float4 chunks over Wq/Wkv/Wo ----
        int i = (blockIdx.x - 1024) * 256 + threadIdx.x;
        const float* src;
        _Float16* dst;
        float sc = 1.f;
        int off;
        if (i < 65536)       { src = Wq;  dst = Wqh;  off = i;          sc = 0.125f; }
        else if (i < 196608) { src = Wkv; dst = Wkvh; off = i - 65536;  }
        else                 { src = Wo;  dst = Woh;  off = i - 196608; }
        float4 v = ((const float4*)src)[off];
        half4v o;
        o.x = (_Float16)(v.x * sc); o.y = (_Float16)(v.y * sc);
        o.z = (_Float16)(v.z * sc); o.w = (_Float16)(v.w * sc);
        ((half4v*)dst)[off] = o;
    }
}

// ---------------------------------------------------------------------------
// LayerNorm + FiLM + seq_mask -> f16 xnh;  ALSO emits raw x as f16 (xh)
// ---------------------------------------------------------------------------
__global__ __launch_bounds__(256)
void ln_film_kernel(const float* __restrict__ x,
                    const float* __restrict__ gamma,
                    const float* __restrict__ film,
                    const float* __restrict__ seq_mask,
                    _Float16* __restrict__ xnh,
                    _Float16* __restrict__ xh) {
    int row = blockIdx.x;           // b*N + i
    int b = row >> 10;
    int t = threadIdx.x;
    const float* xr = x + (size_t)row * D_;
    float v0 = xr[t];
    float v1 = xr[t + 256];
    xh[(size_t)row * D_ + t]       = (_Float16)v0;
    xh[(size_t)row * D_ + t + 256] = (_Float16)v1;
    float s = v0 + v1;
    float sq = v0 * v0 + v1 * v1;
    int lane = t & 63, wave = t >> 6;
    #pragma unroll
    for (int off = 32; off; off >>= 1) {
        s  += __shfl_down(s, off);
        sq += __shfl_down(sq, off);
    }
    __shared__ float rs[4], rq[4];
    if (lane == 0) { rs[wave] = s; rq[wave] = sq; }
    __syncthreads();
    float mu  = (rs[0] + rs[1] + rs[2] + rs[3]) * (1.f / D_);
    float ex2 = (rq[0] + rq[1] + rq[2] + rq[3]) * (1.f / D_);
    float var = ex2 - mu * mu;
    float rstd = rsqrtf(var + EPS_);
    float mrow = seq_mask[row];
    const float* scale = film + (size_t)b * 2 * D_;
    const float* shift = scale + D_;
    {
        int d = t;
        float val = (v0 - mu) * rstd * gamma[d];
        val = val * (scale[d] + 1.f) + shift[d];
        xnh[(size_t)row * D_ + d] = (_Float16)(val * mrow);
    }
    {
        int d = t + 256;
        float val = (v1 - mu) * rstd * gamma[d];
        val = val * (scale[d] + 1.f) + shift[d];
        xnh[(size_t)row * D_ + d] = (_Float16)(val * mrow);
    }
}

// ---------------------------------------------------------------------------
// MFMA f16 GEMM tile body:  C[M,Nn] = A[M,K] @ Bt[Nn,K]^T  (output type OUTT)
// 128x128 tile, BK=32, 256 threads = 4 waves, each wave 64x64 (4x4 MFMA 16x16x32)
// ---------------------------------------------------------------------------
#define LDK 40
template <typename OUTT>
__device__ __forceinline__
void gemm_tile(const _Float16* __restrict__ A,
               const _Float16* __restrict__ Bt,
               OUTT* __restrict__ C,
               int M, int Nn, int K, int bx, int by,
               _Float16* As, _Float16* Bs) {
    int t = threadIdx.x;
    int wave = t >> 6, lane = t & 63;
    int quad = lane >> 4, l16 = lane & 15;
    int m0 = by * 128, n0 = bx * 128;
    int wm = (wave >> 1) * 64, wn = (wave & 1) * 64;

    floatx4 acc[4][4];
    #pragma unroll
    for (int i = 0; i < 4; ++i)
        #pragma unroll
        for (int j = 0; j < 4; ++j)
            acc[i][j] = (floatx4){0.f, 0.f, 0.f, 0.f};

    int row0 = t >> 2;                 // 0..63
    int seg0 = (t & 3) * 8;            // halves within BK

    for (int k0 = 0; k0 < K; k0 += 32) {
        half8v a0 = *(const half8v*)(A  + (size_t)(m0 + row0)      * K + k0 + seg0);
        half8v a1 = *(const half8v*)(A  + (size_t)(m0 + row0 + 64) * K + k0 + seg0);
        half8v b0 = *(const half8v*)(Bt + (size_t)(n0 + row0)      * K + k0 + seg0);
        half8v b1 = *(const half8v*)(Bt + (size_t)(n0 + row0 + 64) * K + k0 + seg0);
        __syncthreads();   // previous-iter fragment reads complete
        *(half8v*)(As + row0 * LDK + seg0)        = a0;
        *(half8v*)(As + (row0 + 64) * LDK + seg0) = a1;
        *(half8v*)(Bs + row0 * LDK + seg0)        = b0;
        *(half8v*)(Bs + (row0 + 64) * LDK + seg0) = b1;
        __syncthreads();   // staging visible

        half8v af[4], bf[4];
        #pragma unroll
        for (int i = 0; i < 4; ++i)
            af[i] = *(half8v*)(As + (wm + i * 16 + l16) * LDK + quad * 8);
        #pragma unroll
        for (int j = 0; j < 4; ++j)
            bf[j] = *(half8v*)(Bs + (wn + j * 16 + l16) * LDK + quad * 8);
        #pragma unroll
        for (int i = 0; i < 4; ++i)
            #pragma unroll
            for (int j = 0; j < 4; ++j)
                acc[i][j] = __builtin_amdgcn_mfma_f32_16x16x32_f16(
                    af[i], bf[j], acc[i][j], 0, 0, 0);
    }

    // C/D layout: col = lane&15, row = quad*4 + reg
    #pragma unroll
    for (int i = 0; i < 4; ++i)
        #pragma unroll
        for (int j = 0; j < 4; ++j)
            #pragma unroll
            for (int r = 0; r < 4; ++r) {
                int grow = m0 + wm + i * 16 + quad * 4 + r;
                int gcol = n0 + wn + j * 16 + l16;
                C[(size_t)grow * Nn + gcol] = (OUTT)acc[i][j][r];
            }
}

// ---------------------------------------------------------------------------
// Fused launch 3: blocks 0..383   -> projection GEMMs (Q, K, V^T)
//                 blocks 384..4479 -> bias projection (streaming, HBM-bound)
// Independent work co-dispatched so the MFMA tiles ride along while the
// bias blocks saturate HBM (single-stream overlap without events).
// LDS arena overlaid: gemm needs 2*128*LDK f16 = 20.5 KB; bias needs 544 B.
// ---------------------------------------------------------------------------
__global__ __launch_bounds__(256)
void projbias_kernel(const _Float16* __restrict__ xnh,
                     const _Float16* __restrict__ xh,
                     const _Float16* __restrict__ Wqh,
                     const _Float16* __restrict__ Wkvh,
                     _Float16* __restrict__ qh,
                     _Float16* __restrict__ kh,
                     _Float16* __restrict__ vth,
                     const float* __restrict__ ab,
                     const float* __restrict__ seq_mask,
                     const float* __restrict__ Wb,
                     const float* __restrict__ bb,
                     __hip_bfloat16* __restrict__ pb) {
    __shared__ char smem[2 * 128 * LDK * 2];   // 20.5 KB arena
    int z = blockIdx.x;
    if (z < 384) {
        _Float16* As = (_Float16*)smem;
        _Float16* Bs = As + 128 * LDK;
        if (z < 128) {
            gemm_tile<_Float16>(xnh, Wqh, qh, 4096, 512, 512, z & 3, z >> 2, As, Bs);
        } else if (z < 256) {
            int y = z - 128;
            gemm_tile<_Float16>(xh, Wkvh, kh, 4096, 512, 512, y & 3, y >> 2, As, Bs);
        } else {
            int y = z - 256;
            gemm_tile<_Float16>(Wkvh + 512 * 512, xh, vth, 512, 4096, 512,
                                y & 31, y >> 5, As, Bs);
        }
        return;
    }
    // ---- bias projection ----
    float* wbs = (float*)smem;           // [8][16]
    float* bbs = wbs + 128;              // [8]
    int blk = z - 384;         // b*1024 + i
    int b = blk >> 10;
    int i = blk & 1023;
    int t = threadIdx.x;
    if (t < 128) wbs[t] = Wb[t];
    if (t < 8)   bbs[t] = bb[t];
    __syncthreads();

    float accx[8], accy[8], accz[8], accw[8];
    #pragma unroll
    for (int h = 0; h < 8; ++h) { accx[h] = accy[h] = accz[h] = accw[h] = bbs[h]; }

    const float* base = ab + ((size_t)(b * AB_) * N_ + i) * N_ + t * 4;
    #pragma unroll
    for (int a = 0; a < AB_; ++a) {
        float4 v = *(const float4*)(base + (size_t)a * N_ * N_);
        #pragma unroll
        for (int h = 0; h < 8; ++h) {
            float w = wbs[h * 16 + a];
            accx[h] += v.x * w;
            accy[h] += v.y * w;
            accz[h] += v.z * w;
            accw[h] += v.w * w;
        }
    }
    float mq = seq_mask[blk];
    float4 mk = *(const float4*)(seq_mask + b * N_ + t * 4);
    float px = (1.f - mq * mk.x) * NEG_;
    float py = (1.f - mq * mk.y) * NEG_;
    float pz = (1.f - mq * mk.z) * NEG_;
    float pw = (1.f - mq * mk.w) * NEG_;

    #pragma unroll
    for (int h = 0; h < 8; ++h) {
        __hip_bfloat16 tmp[4];
        tmp[0] = __float2bfloat16(accx[h] - px);
        tmp[1] = __float2bfloat16(accy[h] - py);
        tmp[2] = __float2bfloat16(accz[h] - pz);
        tmp[3] = __float2bfloat16(accw[h] - pw);
        size_t off = (((size_t)(b * 8 + h) * N_) + i) * N_ + t * 4;
        *(ushort4*)(pb + off) = *(ushort4*)tmp;
    }
}

__global__ __launch_bounds__(256)
void gemm_f32_kernel(const _Float16* __restrict__ A,
                     const _Float16* __restrict__ Bt,
                     float* __restrict__ C, int M, int Nn, int K) {
    __shared__ _Float16 As[128 * LDK];
    __shared__ _Float16 Bs[128 * LDK];
    gemm_tile<float>(A, Bt, C, M, Nn, K, blockIdx.x, blockIdx.y, As, Bs);
}

// ---------------------------------------------------------------------------
// MFMA flash attention: one block per (b, h, 64-query tile), 4 waves.
// Bias tile (pb) staged through LDS: 2 coalesced uint4 loads/thread,
// double-buffered like K/V. LDS 62 KB -> 2 blocks/CU = grid residency.
// ---------------------------------------------------------------------------
#define LDF 72
#define LDP 72
#define LDV 72
#define LDB 68
__global__ __launch_bounds__(256)
void flash_mfma_kernel(const _Float16* __restrict__ qh,
                       const _Float16* __restrict__ kh,
                       const _Float16* __restrict__ vth,
                       const unsigned short* __restrict__ pb,
                       const float* __restrict__ seq_mask,
                       _Float16* __restrict__ atth) {
    __shared__ _Float16 Ks[2][64 * LDF];
    __shared__ _Float16 Vt[2][64 * LDV];
    __shared__ _Float16 Ps[64 * LDP];
    __shared__ unsigned short PBs[2][64 * LDB];

    int z  = blockIdx.x;
    int qt = z & 15;
    int h  = (z >> 4) & 7;
    int b  = z >> 7;
    int i0 = qt * 64;
    int t  = threadIdx.x;
    int wave = t >> 6, lane = t & 63;
    int quad = lane >> 4, l16 = lane & 15;
    int strip = wave * 16;

    const _Float16* qbase =
        qh + ((size_t)(b * N_ + i0 + strip + l16)) * 512 + h * 64;
    half8v qf[2];
    qf[0] = *(const half8v*)(qbase + quad * 8);
    qf[1] = *(const half8v*)(qbase + 32 + quad * 8);

    const _Float16* kb0 = kh + (size_t)(b * N_) * 512 + h * 64;
    const _Float16* vb0 = vth + (size_t)(h * 64) * 4096 + b * N_;
    int sr = t >> 3;          // 0..31 staging row (K/V)
    int c8 = (t & 7) * 8;     // column segment (halves)

    int pr_row = t >> 2;          // 0..63
    int pr_col = (t & 3) * 16;    // 0/16/32/48
    const unsigned short* pbsrc =
        pb + ((size_t)((b * 8 + h) * N_) + i0 + pr_row) * N_ + pr_col;

    // ---- prefetch tile 0 ----
    half8v kr[2], vr[2];
    #pragma unroll
    for (int l = 0; l < 2; ++l) {
        int r = l * 32 + sr;
        kr[l] = *(const half8v*)(kb0 + (size_t)r * 512 + c8);
        vr[l] = *(const half8v*)(vb0 + (size_t)r * 4096 + c8);
    }
    uint4 pr0 = *(const uint4*)(pbsrc);
    uint4 pr1 = *(const uint4*)(pbsrc + 8);

    float m_r[4], l_r[4];
    floatx4 acco[4];
    #pragma unroll
    for (int r = 0; r < 4; ++r) { m_r[r] = -1e30f; l_r[r] = 0.f; }
    #pragma unroll
    for (int tl = 0; tl < 4; ++tl)
        acco[tl] = (floatx4){0.f, 0.f, 0.f, 0.f};

    for (int jt = 0; jt < 16; ++jt) {
        int cur = jt & 1;
        _Float16* Ksc = Ks[cur];
        _Float16* Vtc = Vt[cur];
        unsigned short* PBc = PBs[cur];
        #pragma unroll
        for (int l = 0; l < 2; ++l) {
            int r = l * 32 + sr;
            *(half8v*)(Ksc + r * LDF + c8) = kr[l];
            *(half8v*)(Vtc + r * LDV + c8) = vr[l];
        }
        {
            unsigned short* dst = PBc + pr_row * LDB + pr_col;
            *(uint2*)(dst)      = *(uint2*)&pr0;
            *(uint2*)(dst + 4)  = *((uint2*)&pr0 + 1);
            *(uint2*)(dst + 8)  = *(uint2*)&pr1;
            *(uint2*)(dst + 12) = *((uint2*)&pr1 + 1);
        }
        __syncthreads();   // the only barrier per tile

        if (jt < 15) {
            int j0n = (jt + 1) * 64;
            #pragma unroll
            for (int l = 0; l < 2; ++l) {
                int r = l * 32 + sr;
                kr[l] = *(const half8v*)(kb0 + (size_t)(j0n + r) * 512 + c8);
                vr[l] = *(const half8v*)(vb0 + (size_t)r * 4096 + j0n + c8);
            }
            pr0 = *(const uint4*)(pbsrc + j0n);
            pr1 = *(const uint4*)(pbsrc + j0n + 8);
        }

        // S accumulator init = bias from LDS (<=2-way banks)
        floatx4 accs[4];
        #pragma unroll
        for (int tl = 0; tl < 4; ++tl)
            #pragma unroll
            for (int r = 0; r < 4; ++r)
                accs[tl][r] = __uint_as_float(
                    (unsigned)PBc[(strip + quad * 4 + r) * LDB + tl * 16 + l16] << 16);

        // ---- S = QK^T + bias via MFMA ----
        __builtin_amdgcn_s_setprio(1);
        #pragma unroll
        for (int c = 0; c < 2; ++c)
            #pragma unroll
            for (int tl = 0; tl < 4; ++tl) {
                half8v kf = *(half8v*)(Ksc + (tl * 16 + l16) * LDF + c * 32 + quad * 8);
                accs[tl] = __builtin_amdgcn_mfma_f32_16x16x32_f16(
                    qf[c], kf, accs[tl], 0, 0, 0);
            }
        __builtin_amdgcn_s_setprio(0);

        // ---- online softmax on C-fragments ----
        float rm[4];
        #pragma unroll
        for (int r = 0; r < 4; ++r)
            rm[r] = fmaxf(fmaxf(accs[0][r], accs[1][r]),
                          fmaxf(accs[2][r], accs[3][r]));
        #pragma unroll
        for (int off = 1; off < 16; off <<= 1)
            #pragma unroll
            for (int r = 0; r < 4; ++r)
                rm[r] = fmaxf(rm[r], __shfl_xor(rm[r], off));
        float alpha[4], rsum[4], pv[4][4];
        #pragma unroll
        for (int r = 0; r < 4; ++r) {
            float mn = fmaxf(m_r[r], rm[r]);
            alpha[r] = __expf(m_r[r] - mn);
            m_r[r] = mn;
            float s = 0.f;
            #pragma unroll
            for (int tl = 0; tl < 4; ++tl) {
                float e = __expf(accs[tl][r] - mn);
                pv[tl][r] = e;
                s += e;
            }
            rsum[r] = s;
        }
        #pragma unroll
        for (int off = 1; off < 16; off <<= 1)
            #pragma unroll
            for (int r = 0; r < 4; ++r)
                rsum[r] += __shfl_xor(rsum[r], off);
        #pragma unroll
        for (int r = 0; r < 4; ++r) {
            l_r[r] = l_r[r] * alpha[r] + rsum[r];
            #pragma unroll
            for (int tl = 0; tl < 4; ++tl) {
                acco[tl][r] *= alpha[r];
                Ps[(strip + quad * 4 + r) * LDP + tl * 16 + l16] =
                    (_Float16)pv[tl][r];
            }
        }
        // Ps is wave-private: within-wave lgkmcnt ordering suffices, no barrier

        // ---- O += P @ V via MFMA (A = P, B = Vt[d][j]) ----
        __builtin_amdgcn_s_setprio(1);
        #pragma unroll
        for (int c = 0; c < 2; ++c) {
            half8v pf = *(half8v*)(Ps + (strip + l16) * LDP + c * 32 + quad * 8);
            #pragma unroll
            for (int tl = 0; tl < 4; ++tl) {
                half8v vf = *(half8v*)(Vtc + (tl * 16 + l16) * LDV + c * 32 + quad * 8);
                acco[tl] = __builtin_amdgcn_mfma_f32_16x16x32_f16(
                    pf, vf, acco[tl], 0, 0, 0);
            }
        }
        __builtin_amdgcn_s_setprio(0);
    }

    // ---- epilogue: normalize, mask, f16 store ----
    #pragma unroll
    for (int r = 0; r < 4; ++r) {
        int row = i0 + strip + quad * 4 + r;
        float msk = seq_mask[b * N_ + row];
        float inv = msk / l_r[r];
        _Float16* ob = atth + ((size_t)(b * N_ + row)) * 512 + h * 64;
        #pragma unroll
        for (int tl = 0; tl < 4; ++tl)
            ob[tl * 16 + l16] = (_Float16)(acco[tl][r] * inv);
    }
}

// ---------------------------------------------------------------------------
extern "C" void kernel_launch(void* const* d_in, const int* in_sizes, int n_in,
                              void* d_out, int out_size, void* d_ws, size_t ws_size,
                              hipStream_t stream) {
    const float* x         = (const float*)d_in[0];
    const float* time_in   = (const float*)d_in[1];
    const float* attn_bias = (const float*)d_in[2];
    const float* seq_mask  = (const float*)d_in[3];
    const float* gamma     = (const float*)d_in[4];
    const float* Wt        = (const float*)d_in[5];
    const float* bt        = (const float*)d_in[6];
    const float* Wq        = (const float*)d_in[7];
    const float* Wkv       = (const float*)d_in[8];
    const float* Wo        = (const float*)d_in[9];
    const float* Wb        = (const float*)d_in[10];
    const float* bb        = (const float*)d_in[11];
    float* out = (float*)d_out;

    char* ws = (char*)d_ws;
    const size_t KB = 1024, MB = 1024 * 1024;
    float*     film = (float*)ws;                                   // 16 KB
    _Float16*  xnh  = (_Float16*)(ws + 16 * KB);                    // 4 MB
    _Float16*  xh   = (_Float16*)(ws + 16 * KB + 4 * MB);           // 4 MB
    _Float16*  Wqh  = (_Float16*)(ws + 16 * KB + 8 * MB);           // 512 KB
    _Float16*  Wkvh = (_Float16*)(ws + 16 * KB + 8 * MB + 512 * KB);// 1 MB
    _Float16*  Woh  = (_Float16*)(ws + 16 * KB + 9 * MB + 512 * KB);// 512 KB
    _Float16*  qh   = (_Float16*)(ws + 16 * KB + 10 * MB);          // 4 MB
    _Float16*  kh   = (_Float16*)(ws + 16 * KB + 14 * MB);          // 4 MB
    _Float16*  vth  = (_Float16*)(ws + 16 * KB + 18 * MB);          // 4 MB [512][4096]
    _Float16*  atth = (_Float16*)(ws + 16 * KB + 22 * MB);          // 4 MB
    __hip_bfloat16* pb = (__hip_bfloat16*)(ws + 16 * KB + 26 * MB); // 64 MB

    film_cvtw_kernel<<<2048, 256, 0, stream>>>(time_in, Wt, bt, film,
                                               Wq, Wkv, Wo, Wqh, Wkvh, Woh);
    ln_film_kernel<<<4096, 256, 0, stream>>>(x, gamma, film, seq_mask, xnh, xh);

    // projections (384 MFMA blocks) + bias projection (4096 streaming blocks)
    // co-dispatched in one launch: independent work, overlapped occupancy
    projbias_kernel<<<4480, 256, 0, stream>>>(xnh, xh, Wqh, Wkvh, qh, kh, vth,
                                              attn_bias, seq_mask, Wb, bb, pb);

    flash_mfma_kernel<<<512, 256, 0, stream>>>(qh, kh, vth,
                                               (const unsigned short*)pb,
                                               seq_mask, atth);

    dim3 go(512 / 128, 4096 / 128);
    gemm_f32_kernel<<<go, 256, 0, stream>>>(atth, Woh, out, 4096, 512, 512);
}

// Round 6
// 462.760 us; speedup vs baseline: 1.0202x; 1.0202x over previous
//
#include <hip/hip_runtime.h>
#include <hip/hip_bf16.h>
#include <math.h>

#define B_  4
#define N_  1024
#define D_  512
#define H_  8
#define DH_ 64
#define TC_ 512
#define AB_ 16
#define EPS_ 1e-5f
#define NEG_ 1e6f

typedef _Float16 half8v __attribute__((ext_vector_type(8)));
typedef _Float16 half4v __attribute__((ext_vector_type(4)));
typedef float floatx4 __attribute__((ext_vector_type(4)));

// ---------------------------------------------------------------------------
// Fused launch 1: blocks 0..1023   -> FiLM precompute
//                 blocks 1024..2047 -> weight f16 conversion (Wq*0.125, Wkv, Wo)
// ---------------------------------------------------------------------------
__global__ __launch_bounds__(256)
void film_cvtw_kernel(const float* __restrict__ time_in,
                      const float* __restrict__ Wt,
                      const float* __restrict__ bt,
                      float* __restrict__ film,
                      const float* __restrict__ Wq, const float* __restrict__ Wkv,
                      const float* __restrict__ Wo,
                      _Float16* __restrict__ Wqh, _Float16* __restrict__ Wkvh,
                      _Float16* __restrict__ Woh) {
    __shared__ float st[TC_];
    if (blockIdx.x < 1024) {
        int b = blockIdx.x >> 8;
        int cblk = blockIdx.x & 255;
        const float* trow = time_in + b * TC_;
        for (int j = threadIdx.x; j < TC_; j += 256) {
            float tv = trow[j];
            st[j] = tv / (1.f + __expf(-tv));
        }
        __syncthreads();
        int wave = threadIdx.x >> 6, lane = threadIdx.x & 63;
        int c = cblk * 4 + wave;
        const float* wrow = Wt + (size_t)c * TC_;
        float acc = 0.f;
        #pragma unroll
        for (int j0 = 0; j0 < TC_; j0 += 64)
            acc += st[j0 + lane] * wrow[j0 + lane];
        #pragma unroll
        for (int off = 32; off; off >>= 1)
            acc += __shfl_down(acc, off);
        if (lane == 0) film[b * 2 * D_ + c] = acc + bt[c];
    } else {
        int i = (blockIdx.x - 1024) * 256 + threadIdx.x;
        const float* src;
        _Float16* dst;
        float sc = 1.f;
        int off;
        if (i < 65536)       { src = Wq;  dst = Wqh;  off = i;          sc = 0.125f; }
        else if (i < 196608) { src = Wkv; dst = Wkvh; off = i - 65536;  }
        else                 { src = Wo;  dst = Woh;  off = i - 196608; }
        float4 v = ((const float4*)src)[off];
        half4v o;
        o.x = (_Float16)(v.x * sc); o.y = (_Float16)(v.y * sc);
        o.z = (_Float16)(v.z * sc); o.w = (_Float16)(v.w * sc);
        ((half4v*)dst)[off] = o;
    }
}

// ---------------------------------------------------------------------------
// LayerNorm + FiLM + seq_mask -> f16 xnh;  ALSO emits raw x as f16 (xh)
// ---------------------------------------------------------------------------
__global__ __launch_bounds__(256)
void ln_film_kernel(const float* __restrict__ x,
                    const float* __restrict__ gamma,
                    const float* __restrict__ film,
                    const float* __restrict__ seq_mask,
                    _Float16* __restrict__ xnh,
                    _Float16* __restrict__ xh) {
    int row = blockIdx.x;           // b*N + i
    int b = row >> 10;
    int t = threadIdx.x;
    const float* xr = x + (size_t)row * D_;
    float v0 = xr[t];
    float v1 = xr[t + 256];
    xh[(size_t)row * D_ + t]       = (_Float16)v0;
    xh[(size_t)row * D_ + t + 256] = (_Float16)v1;
    float s = v0 + v1;
    float sq = v0 * v0 + v1 * v1;
    int lane = t & 63, wave = t >> 6;
    #pragma unroll
    for (int off = 32; off; off >>= 1) {
        s  += __shfl_down(s, off);
        sq += __shfl_down(sq, off);
    }
    __shared__ float rs[4], rq[4];
    if (lane == 0) { rs[wave] = s; rq[wave] = sq; }
    __syncthreads();
    float mu  = (rs[0] + rs[1] + rs[2] + rs[3]) * (1.f / D_);
    float ex2 = (rq[0] + rq[1] + rq[2] + rq[3]) * (1.f / D_);
    float var = ex2 - mu * mu;
    float rstd = rsqrtf(var + EPS_);
    float mrow = seq_mask[row];
    const float* scale = film + (size_t)b * 2 * D_;
    const float* shift = scale + D_;
    {
        int d = t;
        float val = (v0 - mu) * rstd * gamma[d];
        val = val * (scale[d] + 1.f) + shift[d];
        xnh[(size_t)row * D_ + d] = (_Float16)(val * mrow);
    }
    {
        int d = t + 256;
        float val = (v1 - mu) * rstd * gamma[d];
        val = val * (scale[d] + 1.f) + shift[d];
        xnh[(size_t)row * D_ + d] = (_Float16)(val * mrow);
    }
}

// ---------------------------------------------------------------------------
// MFMA f16 GEMM tile body:  C[M,Nn] = A[M,K] @ Bt[Nn,K]^T  (output type OUTT)
// 128x128 tile, BK=32, 256 threads = 4 waves, each wave 64x64 (4x4 MFMA 16x16x32)
// ---------------------------------------------------------------------------
#define LDK 40
template <typename OUTT>
__device__ __forceinline__
void gemm_tile(const _Float16* __restrict__ A,
               const _Float16* __restrict__ Bt,
               OUTT* __restrict__ C,
               int M, int Nn, int K, int bx, int by,
               _Float16* As, _Float16* Bs) {
    int t = threadIdx.x;
    int wave = t >> 6, lane = t & 63;
    int quad = lane >> 4, l16 = lane & 15;
    int m0 = by * 128, n0 = bx * 128;
    int wm = (wave >> 1) * 64, wn = (wave & 1) * 64;

    floatx4 acc[4][4];
    #pragma unroll
    for (int i = 0; i < 4; ++i)
        #pragma unroll
        for (int j = 0; j < 4; ++j)
            acc[i][j] = (floatx4){0.f, 0.f, 0.f, 0.f};

    int row0 = t >> 2;                 // 0..63
    int seg0 = (t & 3) * 8;            // halves within BK

    for (int k0 = 0; k0 < K; k0 += 32) {
        half8v a0 = *(const half8v*)(A  + (size_t)(m0 + row0)      * K + k0 + seg0);
        half8v a1 = *(const half8v*)(A  + (size_t)(m0 + row0 + 64) * K + k0 + seg0);
        half8v b0 = *(const half8v*)(Bt + (size_t)(n0 + row0)      * K + k0 + seg0);
        half8v b1 = *(const half8v*)(Bt + (size_t)(n0 + row0 + 64) * K + k0 + seg0);
        __syncthreads();   // previous-iter fragment reads complete
        *(half8v*)(As + row0 * LDK + seg0)        = a0;
        *(half8v*)(As + (row0 + 64) * LDK + seg0) = a1;
        *(half8v*)(Bs + row0 * LDK + seg0)        = b0;
        *(half8v*)(Bs + (row0 + 64) * LDK + seg0) = b1;
        __syncthreads();   // staging visible

        half8v af[4], bf[4];
        #pragma unroll
        for (int i = 0; i < 4; ++i)
            af[i] = *(half8v*)(As + (wm + i * 16 + l16) * LDK + quad * 8);
        #pragma unroll
        for (int j = 0; j < 4; ++j)
            bf[j] = *(half8v*)(Bs + (wn + j * 16 + l16) * LDK + quad * 8);
        #pragma unroll
        for (int i = 0; i < 4; ++i)
            #pragma unroll
            for (int j = 0; j < 4; ++j)
                acc[i][j] = __builtin_amdgcn_mfma_f32_16x16x32_f16(
                    af[i], bf[j], acc[i][j], 0, 0, 0);
    }

    // C/D layout: col = lane&15, row = quad*4 + reg
    #pragma unroll
    for (int i = 0; i < 4; ++i)
        #pragma unroll
        for (int j = 0; j < 4; ++j)
            #pragma unroll
            for (int r = 0; r < 4; ++r) {
                int grow = m0 + wm + i * 16 + quad * 4 + r;
                int gcol = n0 + wn + j * 16 + l16;
                C[(size_t)grow * Nn + gcol] = (OUTT)acc[i][j][r];
            }
}

// Fused projection GEMMs: z<128 -> Q = xnh@Wq^T (pre-scaled), z<256 -> K,
// z<384 -> V^T = Wv @ x^T (so flash gets V already feature-major).
__global__ __launch_bounds__(256)
void proj3_kernel(const _Float16* __restrict__ xnh,
                  const _Float16* __restrict__ xh,
                  const _Float16* __restrict__ Wqh,
                  const _Float16* __restrict__ Wkvh,
                  _Float16* __restrict__ qh,
                  _Float16* __restrict__ kh,
                  _Float16* __restrict__ vth) {
    __shared__ _Float16 As[128 * LDK];
    __shared__ _Float16 Bs[128 * LDK];
    int z = blockIdx.x;
    if (z < 128) {
        gemm_tile<_Float16>(xnh, Wqh, qh, 4096, 512, 512, z & 3, z >> 2, As, Bs);
    } else if (z < 256) {
        int y = z - 128;
        gemm_tile<_Float16>(xh, Wkvh, kh, 4096, 512, 512, y & 3, y >> 2, As, Bs);
    } else {
        int y = z - 256;
        gemm_tile<_Float16>(Wkvh + 512 * 512, xh, vth, 512, 4096, 512,
                            y & 31, y >> 5, As, Bs);
    }
}

// ---------------------------------------------------------------------------
// Output GEMM: C[4096,512] = A[4096,512] @ Bt[512,512]^T, fp32 out.
// 128x64 tiles -> 256 blocks (2x the fill of 128x128). 4 waves as 2x2,
// each wave 64x32 (4x2 MFMA 16x16x32).
// ---------------------------------------------------------------------------
__global__ __launch_bounds__(256)
void gemm_out_kernel(const _Float16* __restrict__ A,
                     const _Float16* __restrict__ Bt,
                     float* __restrict__ C) {
    __shared__ _Float16 As[128 * LDK];
    __shared__ _Float16 Bs[64 * LDK];
    const int K = 512, Nn = 512;
    int t = threadIdx.x;
    int wave = t >> 6, lane = t & 63;
    int quad = lane >> 4, l16 = lane & 15;
    int m0 = blockIdx.y * 128, n0 = blockIdx.x * 64;
    int wm = (wave >> 1) * 64, wn = (wave & 1) * 32;

    floatx4 acc[4][2];
    #pragma unroll
    for (int i = 0; i < 4; ++i)
        #pragma unroll
        for (int j = 0; j < 2; ++j)
            acc[i][j] = (floatx4){0.f, 0.f, 0.f, 0.f};

    int row0 = t >> 2;
    int seg0 = (t & 3) * 8;

    for (int k0 = 0; k0 < K; k0 += 32) {
        half8v a0 = *(const half8v*)(A  + (size_t)(m0 + row0)      * K + k0 + seg0);
        half8v a1 = *(const half8v*)(A  + (size_t)(m0 + row0 + 64) * K + k0 + seg0);
        half8v b0 = *(const half8v*)(Bt + (size_t)(n0 + row0)      * K + k0 + seg0);
        __syncthreads();
        *(half8v*)(As + row0 * LDK + seg0)        = a0;
        *(half8v*)(As + (row0 + 64) * LDK + seg0) = a1;
        *(half8v*)(Bs + row0 * LDK + seg0)        = b0;
        __syncthreads();

        half8v af[4], bf[2];
        #pragma unroll
        for (int i = 0; i < 4; ++i)
            af[i] = *(half8v*)(As + (wm + i * 16 + l16) * LDK + quad * 8);
        #pragma unroll
        for (int j = 0; j < 2; ++j)
            bf[j] = *(half8v*)(Bs + (wn + j * 16 + l16) * LDK + quad * 8);
        #pragma unroll
        for (int i = 0; i < 4; ++i)
            #pragma unroll
            for (int j = 0; j < 2; ++j)
                acc[i][j] = __builtin_amdgcn_mfma_f32_16x16x32_f16(
                    af[i], bf[j], acc[i][j], 0, 0, 0);
    }

    #pragma unroll
    for (int i = 0; i < 4; ++i)
        #pragma unroll
        for (int j = 0; j < 2; ++j)
            #pragma unroll
            for (int r = 0; r < 4; ++r) {
                int grow = m0 + wm + i * 16 + quad * 4 + r;
                int gcol = n0 + wn + j * 16 + l16;
                C[(size_t)grow * Nn + gcol] = acc[i][j][r];
            }
}

// ---------------------------------------------------------------------------
// bias projection: pb[b,h,i,j] = sum_a attn_bias[b,a,i,j]*Wb[h,a] + bb[h]
//                                - (1 - mq*mk)*NEG          (stored as bf16)
// ---------------------------------------------------------------------------
__global__ __launch_bounds__(256)
void bias_proj_kernel(const float* __restrict__ ab,
                      const float* __restrict__ seq_mask,
                      const float* __restrict__ Wb,
                      const float* __restrict__ bb,
                      __hip_bfloat16* __restrict__ pb) {
    __shared__ float wbs[8][16];
    __shared__ float bbs[8];
    int blk = blockIdx.x;      // b*1024 + i
    int b = blk >> 10;
    int i = blk & 1023;
    int t = threadIdx.x;
    if (t < 128) wbs[t >> 4][t & 15] = Wb[t];
    if (t < 8)   bbs[t] = bb[t];
    __syncthreads();

    float accx[8], accy[8], accz[8], accw[8];
    #pragma unroll
    for (int h = 0; h < 8; ++h) { accx[h] = accy[h] = accz[h] = accw[h] = bbs[h]; }

    const float* base = ab + ((size_t)(b * AB_) * N_ + i) * N_ + t * 4;
    #pragma unroll
    for (int a = 0; a < AB_; ++a) {
        float4 v = *(const float4*)(base + (size_t)a * N_ * N_);
        #pragma unroll
        for (int h = 0; h < 8; ++h) {
            float w = wbs[h][a];
            accx[h] += v.x * w;
            accy[h] += v.y * w;
            accz[h] += v.z * w;
            accw[h] += v.w * w;
        }
    }
    float mq = seq_mask[blk];
    float4 mk = *(const float4*)(seq_mask + b * N_ + t * 4);
    float px = (1.f - mq * mk.x) * NEG_;
    float py = (1.f - mq * mk.y) * NEG_;
    float pz = (1.f - mq * mk.z) * NEG_;
    float pw = (1.f - mq * mk.w) * NEG_;

    #pragma unroll
    for (int h = 0; h < 8; ++h) {
        __hip_bfloat16 tmp[4];
        tmp[0] = __float2bfloat16(accx[h] - px);
        tmp[1] = __float2bfloat16(accy[h] - py);
        tmp[2] = __float2bfloat16(accz[h] - pz);
        tmp[3] = __float2bfloat16(accw[h] - pw);
        size_t off = (((size_t)(b * 8 + h) * N_) + i) * N_ + t * 4;
        *(ushort4*)(pb + off) = *(ushort4*)tmp;
    }
}

// ---------------------------------------------------------------------------
// MFMA flash attention: one block per (b, h, 64-query tile), 4 waves.
// Bias tile (pb) staged through LDS (coalesced uint4 loads), double-buffered
// like K/V. Next-tile global prefetches issued BEFORE the barrier so loads
// fly while waves wait. LDS 62 KB -> 2 blocks/CU = grid residency.
// ---------------------------------------------------------------------------
#define LDF 72
#define LDP 72
#define LDV 72
#define LDB 68
__global__ __launch_bounds__(256)
void flash_mfma_kernel(const _Float16* __restrict__ qh,
                       const _Float16* __restrict__ kh,
                       const _Float16* __restrict__ vth,
                       const unsigned short* __restrict__ pb,
                       const float* __restrict__ seq_mask,
                       _Float16* __restrict__ atth) {
    __shared__ _Float16 Ks[2][64 * LDF];
    __shared__ _Float16 Vt[2][64 * LDV];
    __shared__ _Float16 Ps[64 * LDP];
    __shared__ unsigned short PBs[2][64 * LDB];

    int z  = blockIdx.x;
    int qt = z & 15;
    int h  = (z >> 4) & 7;
    int b  = z >> 7;
    int i0 = qt * 64;
    int t  = threadIdx.x;
    int wave = t >> 6, lane = t & 63;
    int quad = lane >> 4, l16 = lane & 15;
    int strip = wave * 16;

    const _Float16* qbase =
        qh + ((size_t)(b * N_ + i0 + strip + l16)) * 512 + h * 64;
    half8v qf[2];
    qf[0] = *(const half8v*)(qbase + quad * 8);
    qf[1] = *(const half8v*)(qbase + 32 + quad * 8);

    const _Float16* kb0 = kh + (size_t)(b * N_) * 512 + h * 64;
    const _Float16* vb0 = vth + (size_t)(h * 64) * 4096 + b * N_;
    int sr = t >> 3;          // 0..31 staging row (K/V)
    int c8 = (t & 7) * 8;     // column segment (halves)

    int pr_row = t >> 2;          // 0..63
    int pr_col = (t & 3) * 16;    // 0/16/32/48
    const unsigned short* pbsrc =
        pb + ((size_t)((b * 8 + h) * N_) + i0 + pr_row) * N_ + pr_col;

    // ---- prefetch tile 0 ----
    half8v kr[2], vr[2];
    #pragma unroll
    for (int l = 0; l < 2; ++l) {
        int r = l * 32 + sr;
        kr[l] = *(const half8v*)(kb0 + (size_t)r * 512 + c8);
        vr[l] = *(const half8v*)(vb0 + (size_t)r * 4096 + c8);
    }
    uint4 pr0 = *(const uint4*)(pbsrc);
    uint4 pr1 = *(const uint4*)(pbsrc + 8);

    float m_r[4], l_r[4];
    floatx4 acco[4];
    #pragma unroll
    for (int r = 0; r < 4; ++r) { m_r[r] = -1e30f; l_r[r] = 0.f; }
    #pragma unroll
    for (int tl = 0; tl < 4; ++tl)
        acco[tl] = (floatx4){0.f, 0.f, 0.f, 0.f};

    for (int jt = 0; jt < 16; ++jt) {
        int cur = jt & 1;
        _Float16* Ksc = Ks[cur];
        _Float16* Vtc = Vt[cur];
        unsigned short* PBc = PBs[cur];
        #pragma unroll
        for (int l = 0; l < 2; ++l) {
            int r = l * 32 + sr;
            *(half8v*)(Ksc + r * LDF + c8) = kr[l];
            *(half8v*)(Vtc + r * LDV + c8) = vr[l];
        }
        {
            unsigned short* dst = PBc + pr_row * LDB + pr_col;
            *(uint2*)(dst)      = *(uint2*)&pr0;
            *(uint2*)(dst + 4)  = *((uint2*)&pr0 + 1);
            *(uint2*)(dst + 8)  = *(uint2*)&pr1;
            *(uint2*)(dst + 12) = *((uint2*)&pr1 + 1);
        }
        // issue next tile's global loads BEFORE the barrier (fly during wait)
        if (jt < 15) {
            int j0n = (jt + 1) * 64;
            #pragma unroll
            for (int l = 0; l < 2; ++l) {
                int r = l * 32 + sr;
                kr[l] = *(const half8v*)(kb0 + (size_t)(j0n + r) * 512 + c8);
                vr[l] = *(const half8v*)(vb0 + (size_t)r * 4096 + j0n + c8);
            }
            pr0 = *(const uint4*)(pbsrc + j0n);
            pr1 = *(const uint4*)(pbsrc + j0n + 8);
        }
        __syncthreads();   // the only barrier per tile

        // S accumulator init = bias from LDS (<=2-way banks)
        floatx4 accs[4];
        #pragma unroll
        for (int tl = 0; tl < 4; ++tl)
            #pragma unroll
            for (int r = 0; r < 4; ++r)
                accs[tl][r] = __uint_as_float(
                    (unsigned)PBc[(strip + quad * 4 + r) * LDB + tl * 16 + l16] << 16);

        // ---- S = QK^T + bias via MFMA ----
        __builtin_amdgcn_s_setprio(1);
        #pragma unroll
        for (int c = 0; c < 2; ++c)
            #pragma unroll
            for (int tl = 0; tl < 4; ++tl) {
                half8v kf = *(half8v*)(Ksc + (tl * 16 + l16) * LDF + c * 32 + quad * 8);
                accs[tl] = __builtin_amdgcn_mfma_f32_16x16x32_f16(
                    qf[c], kf, accs[tl], 0, 0, 0);
            }
        __builtin_amdgcn_s_setprio(0);

        // ---- online softmax on C-fragments ----
        float rm[4];
        #pragma unroll
        for (int r = 0; r < 4; ++r)
            rm[r] = fmaxf(fmaxf(accs[0][r], accs[1][r]),
                          fmaxf(accs[2][r], accs[3][r]));
        #pragma unroll
        for (int off = 1; off < 16; off <<= 1)
            #pragma unroll
            for (int r = 0; r < 4; ++r)
                rm[r] = fmaxf(rm[r], __shfl_xor(rm[r], off));
        float alpha[4], rsum[4], pv[4][4];
        #pragma unroll
        for (int r = 0; r < 4; ++r) {
            float mn = fmaxf(m_r[r], rm[r]);
            alpha[r] = __expf(m_r[r] - mn);
            m_r[r] = mn;
            float s = 0.f;
            #pragma unroll
            for (int tl = 0; tl < 4; ++tl) {
                float e = __expf(accs[tl][r] - mn);
                pv[tl][r] = e;
                s += e;
            }
            rsum[r] = s;
        }
        #pragma unroll
        for (int off = 1; off < 16; off <<= 1)
            #pragma unroll
            for (int r = 0; r < 4; ++r)
                rsum[r] += __shfl_xor(rsum[r], off);
        #pragma unroll
        for (int r = 0; r < 4; ++r) {
            l_r[r] = l_r[r] * alpha[r] + rsum[r];
            #pragma unroll
            for (int tl = 0; tl < 4; ++tl) {
                acco[tl][r] *= alpha[r];
                Ps[(strip + quad * 4 + r) * LDP + tl * 16 + l16] =
                    (_Float16)pv[tl][r];
            }
        }
        // Ps is wave-private: within-wave lgkmcnt ordering suffices, no barrier

        // ---- O += P @ V via MFMA (A = P, B = Vt[d][j]) ----
        __builtin_amdgcn_s_setprio(1);
        #pragma unroll
        for (int c = 0; c < 2; ++c) {
            half8v pf = *(half8v*)(Ps + (strip + l16) * LDP + c * 32 + quad * 8);
            #pragma unroll
            for (int tl = 0; tl < 4; ++tl) {
                half8v vf = *(half8v*)(Vtc + (tl * 16 + l16) * LDV + c * 32 + quad * 8);
                acco[tl] = __builtin_amdgcn_mfma_f32_16x16x32_f16(
                    pf, vf, acco[tl], 0, 0, 0);
            }
        }
        __builtin_amdgcn_s_setprio(0);
    }

    // ---- epilogue: normalize, mask, f16 store ----
    #pragma unroll
    for (int r = 0; r < 4; ++r) {
        int row = i0 + strip + quad * 4 + r;
        float msk = seq_mask[b * N_ + row];
        float inv = msk / l_r[r];
        _Float16* ob = atth + ((size_t)(b * N_ + row)) * 512 + h * 64;
        #pragma unroll
        for (int tl = 0; tl < 4; ++tl)
            ob[tl * 16 + l16] = (_Float16)(acco[tl][r] * inv);
    }
}

// ---------------------------------------------------------------------------
extern "C" void kernel_launch(void* const* d_in, const int* in_sizes, int n_in,
                              void* d_out, int out_size, void* d_ws, size_t ws_size,
                              hipStream_t stream) {
    const float* x         = (const float*)d_in[0];
    const float* time_in   = (const float*)d_in[1];
    const float* attn_bias = (const float*)d_in[2];
    const float* seq_mask  = (const float*)d_in[3];
    const float* gamma     = (const float*)d_in[4];
    const float* Wt        = (const float*)d_in[5];
    const float* bt        = (const float*)d_in[6];
    const float* Wq        = (const float*)d_in[7];
    const float* Wkv       = (const float*)d_in[8];
    const float* Wo        = (const float*)d_in[9];
    const float* Wb        = (const float*)d_in[10];
    const float* bb        = (const float*)d_in[11];
    float* out = (float*)d_out;

    char* ws = (char*)d_ws;
    const size_t KB = 1024, MB = 1024 * 1024;
    float*     film = (float*)ws;                                   // 16 KB
    _Float16*  xnh  = (_Float16*)(ws + 16 * KB);                    // 4 MB
    _Float16*  xh   = (_Float16*)(ws + 16 * KB + 4 * MB);           // 4 MB
    _Float16*  Wqh  = (_Float16*)(ws + 16 * KB + 8 * MB);           // 512 KB
    _Float16*  Wkvh = (_Float16*)(ws + 16 * KB + 8 * MB + 512 * KB);// 1 MB
    _Float16*  Woh  = (_Float16*)(ws + 16 * KB + 9 * MB + 512 * KB);// 512 KB
    _Float16*  qh   = (_Float16*)(ws + 16 * KB + 10 * MB);          // 4 MB
    _Float16*  kh   = (_Float16*)(ws + 16 * KB + 14 * MB);          // 4 MB
    _Float16*  vth  = (_Float16*)(ws + 16 * KB + 18 * MB);          // 4 MB [512][4096]
    _Float16*  atth = (_Float16*)(ws + 16 * KB + 22 * MB);          // 4 MB
    __hip_bfloat16* pb = (__hip_bfloat16*)(ws + 16 * KB + 26 * MB); // 64 MB

    film_cvtw_kernel<<<2048, 256, 0, stream>>>(time_in, Wt, bt, film,
                                               Wq, Wkv, Wo, Wqh, Wkvh, Woh);
    ln_film_kernel<<<4096, 256, 0, stream>>>(x, gamma, film, seq_mask, xnh, xh);

    proj3_kernel<<<384, 256, 0, stream>>>(xnh, xh, Wqh, Wkvh, qh, kh, vth);
    bias_proj_kernel<<<4096, 256, 0, stream>>>(attn_bias, seq_mask, Wb, bb, pb);

    flash_mfma_kernel<<<512, 256, 0, stream>>>(qh, kh, vth,
                                               (const unsigned short*)pb,
                                               seq_mask, atth);

    dim3 go(512 / 64, 4096 / 128);
    gemm_out_kernel<<<go, 256, 0, stream>>>(atth, Woh, out);
}